// Round 11
// baseline (283.880 us; speedup 1.0000x reference)
//
#include <hip/hip_runtime.h>
#include <stdint.h>
#include <math.h>

#define BDIM   2
#define CDIM   16
#define INS    64
#define OUTS   20
#define NPTS   8000          // 20^3
#define TOTN   (BDIM*NPTS)   // 16000

using f64x4 = __attribute__((ext_vector_type(4))) double;

#define MFMA64(a, b, c) __builtin_amdgcn_mfma_f64_16x16x4f64((a), (b), (c), 0, 0, 0)

// ---------------- ws layout (bytes, all 8B-aligned) ----------------
// sfeat(-2x): 0        +2,048,000   (B,N,C) f64, pre-scaled by -2
// tfeat     : 2048000  +2,048,000   (B,N,C) f64
// t2        : 4096000  +128,000     (B,N)   f64
// pscore    : 4224000  +B*nchunk*N*8
// pidx      : ...      +B*nchunk*N*4
// lpart     : ...      +504
// ~9.03 MB at nchunk=25 (fallback nchunk=5 -> ~5.19 MB)

// Trilinear resize 64^3 -> 20^3 matching jax.image.resize(method='trilinear',
// antialias=True). All math in f64. Source features stored pre-scaled by -2
// (exact: power of two) so the MFMA computes t2 - 2*s.t directly.
__global__ void k_resize(const float* __restrict__ src, const float* __restrict__ tgt,
                         double* __restrict__ sfeat2, double* __restrict__ tfeat) {
    __shared__ double wts[OUTS][8];
    __shared__ int    st[OUTS];
    __shared__ int    cnt[OUTS];
    int tid = threadIdx.x;
    if (tid < OUTS) {
        double sample = (tid + 0.5) * 3.2 - 0.5;
        int lo = (int)ceil(sample - 3.2);
        int hi = (int)floor(sample + 3.2);
        if (lo < 0) lo = 0;
        if (hi > INS - 1) hi = INS - 1;
        int c = hi - lo + 1;           // <= 7
        double w[8];
        double sum = 0.0;
        for (int k = 0; k < 8; ++k) {
            double ww = 0.0;
            if (k < c) {
                double x = fabs(sample - (double)(lo + k)) * (1.0 / 3.2);
                ww = (x < 1.0) ? (1.0 - x) : 0.0;
            }
            w[k] = ww; sum += ww;
        }
        for (int k = 0; k < 8; ++k) wts[tid][k] = w[k] / sum;
        st[tid] = lo; cnt[tid] = c;
    }
    __syncthreads();

    int gid = blockIdx.x * blockDim.x + tid;     // [sel][b][c][od][oh][ow], 512000 total
    int ow = gid % OUTS; int r = gid / OUTS;
    int oh = r % OUTS;  r /= OUTS;
    int od = r % OUTS;  r /= OUTS;
    int c  = r % CDIM;  r /= CDIM;
    int b  = r % BDIM;  r /= BDIM;
    int sel = r;                                  // 0=src, 1=tgt

    const float* in   = sel ? tgt : src;
    double*      outf = sel ? tfeat : sfeat2;

    const float* base = in + (((size_t)(b * CDIM + c)) << 18);   // * 64*64*64
    int sd = st[od], sh = st[oh], sw = st[ow];
    int cd = cnt[od], ch = cnt[oh], cw = cnt[ow];
    double wwv[8];
    for (int k = 0; k < 8; ++k) wwv[k] = wts[ow][k];

    double acc = 0.0;
    for (int id = 0; id < cd; ++id) {
        double wd = wts[od][id];
        const float* pd = base + ((size_t)(sd + id) << 12);
        for (int ih = 0; ih < ch; ++ih) {
            double wdh = wd * wts[oh][ih];
            const float* row = pd + ((sh + ih) << 6) + sw;
            for (int iw = 0; iw < cw; ++iw)
                acc = fma(wdh * wwv[iw], (double)row[iw], acc);
        }
    }
    if (sel == 0) acc = -2.0 * acc;               // exact scale
    int n = (od * OUTS + oh) * OUTS + ow;
    outf[((size_t)(b * NPTS + n)) * CDIM + c] = acc;
}

__global__ void k_t2(const double* __restrict__ tfeat, double* __restrict__ t2) {
    int i = blockIdx.x * blockDim.x + threadIdx.x;
    if (i >= TOTN) return;
    const double* p = tfeat + (size_t)i * CDIM;
    double a = 0, b = 0, c = 0, d = 0;
#pragma unroll
    for (int k = 0; k < 4; ++k) {
        a = fma(p[4*k+0], p[4*k+0], a);
        b = fma(p[4*k+1], p[4*k+1], b);
        c = fma(p[4*k+2], p[4*k+2], c);
        d = fma(p[4*k+3], p[4*k+3], d);
    }
    t2[i] = (a + b) + (c + d);
}

// f64-MFMA argmin, round-11 structure:
//  - calibrated layout + pi-permuted A rows (static D-slot -> m map),
//  - body = 64 m: 4 independent 4-deep MFMA chains (16 MFMA ~ 256 cy issue)
//    so the 1-body ping-pong prefetch lead covers L2 latency,
//  - t2 folded into MFMA C-operand; per-slot (best,bp) mins, no serial chain.
// Ties exact: strict < keeps earliest body per slot; slot fold and cross-lane
// merges lexicographic (score, m) -> first-occurrence argmin.
__global__ __launch_bounds__(256, 2) void k_argmin(const double* __restrict__ sfeat2,
                                                   const double* __restrict__ tfeat,
                                                   const double* __restrict__ t2,
                                                   double* __restrict__ pscore,
                                                   int* __restrict__ pidx,
                                                   int mchunk, int nchunk) {
    int b     = blockIdx.z;
    int chunk = blockIdx.y;
    int lane  = threadIdx.x & 63;
    int wp    = threadIdx.x >> 6;                // 0..3
    int n0    = (blockIdx.x << 6) + (wp << 4);   // wave's 16-n strip
    int lr    = lane & 15;                       // fragment feed index
    int lq    = lane >> 4;                       // k-group 0..3

    // ---- layout calibration + pi table ----
    f64x4 z = {0.0, 0.0, 0.0, 0.0};
    f64x4 calA = MFMA64((double)lr, 0.25, z);
    f64x4 calB = MFMA64(0.25, (double)lr, z);
    int ncol = (int)(calB[0] + 0.5);

    __shared__ int ptab[16];
#pragma unroll
    for (int j = 0; j < 4; ++j) {
        int r = (int)(calA[j] + 0.5);            // hardware feed-row of slot j
        ptab[r] = (lq << 2) + j;                 // pi: feed-row -> desired m-offset
    }
    __syncthreads();
    int prow = ptab[lr];                         // A-row permutation for this lane

    // B fragments: s2^T, k = 4*lq + kb -> contiguous 32B per lane
    const double* sb = sfeat2 + ((size_t)(b * NPTS + n0 + lr)) * CDIM + (lq << 2);
    double bf0 = sb[0], bf1 = sb[1], bf2 = sb[2], bf3 = sb[3];

    const double* tb  = tfeat + (size_t)b * NPTS * CDIM;
    const double* t2b = t2 + (size_t)b * NPTS;

    int mbase = chunk * mchunk;
    int iters = mchunk >> 6;                     // bodies of 64 m

    // lane-constant stream pointers
    const double* tA = tb + ((size_t)(mbase + prow)) * CDIM + (lq << 2);
    const double* tV = t2b + mbase + (lq << 2);

    double best[16];
    int    bp[16];
#pragma unroll
    for (int s = 0; s < 16; ++s) { best[s] = 1e300; bp[s] = 0; }

    f64x4 aE0, aE1, aE2, aE3, vE0, vE1, vE2, vE3;
    f64x4 aO0, aO1, aO2, aO3, vO0, vO1, vO2, vO3;

#define LOADP(P, A0, A1, A2, A3, V0, V1, V2, V3)                    \
    {  const double* pa_ = tA + (size_t)((P) << 6) * CDIM;          \
       A0 = *(const f64x4*)(pa_);                                   \
       A1 = *(const f64x4*)(pa_ + (CDIM << 4));                     \
       A2 = *(const f64x4*)(pa_ + (CDIM << 5));                     \
       A3 = *(const f64x4*)(pa_ + 3 * (CDIM << 4));                 \
       const double* pv_ = tV + ((P) << 6);                         \
       V0 = *(const f64x4*)(pv_);                                   \
       V1 = *(const f64x4*)(pv_ + 16);                              \
       V2 = *(const f64x4*)(pv_ + 32);                              \
       V3 = *(const f64x4*)(pv_ + 48); }

#define BODYP(P, A0, A1, A2, A3, V0, V1, V2, V3)                    \
    {  f64x4 ac0 = V0, ac1 = V1, ac2 = V2, ac3 = V3;                \
       ac0 = MFMA64(A0[0], bf0, ac0);                               \
       ac1 = MFMA64(A1[0], bf0, ac1);                               \
       ac2 = MFMA64(A2[0], bf0, ac2);                               \
       ac3 = MFMA64(A3[0], bf0, ac3);                               \
       ac0 = MFMA64(A0[1], bf1, ac0);                               \
       ac1 = MFMA64(A1[1], bf1, ac1);                               \
       ac2 = MFMA64(A2[1], bf1, ac2);                               \
       ac3 = MFMA64(A3[1], bf1, ac3);                               \
       ac0 = MFMA64(A0[2], bf2, ac0);                               \
       ac1 = MFMA64(A1[2], bf2, ac1);                               \
       ac2 = MFMA64(A2[2], bf2, ac2);                               \
       ac3 = MFMA64(A3[2], bf2, ac3);                               \
       ac0 = MFMA64(A0[3], bf3, ac0);                               \
       ac1 = MFMA64(A1[3], bf3, ac1);                               \
       ac2 = MFMA64(A2[3], bf3, ac2);                               \
       ac3 = MFMA64(A3[3], bf3, ac3);                               \
       _Pragma("unroll")                                            \
       for (int j = 0; j < 4; ++j) {                                \
           if (ac0[j] < best[j])      { best[j]      = ac0[j]; bp[j]      = (P); } \
           if (ac1[j] < best[4 + j])  { best[4 + j]  = ac1[j]; bp[4 + j]  = (P); } \
           if (ac2[j] < best[8 + j])  { best[8 + j]  = ac2[j]; bp[8 + j]  = (P); } \
           if (ac3[j] < best[12 + j]) { best[12 + j] = ac3[j]; bp[12 + j] = (P); } \
       } }

    LOADP(0, aE0, aE1, aE2, aE3, vE0, vE1, vE2, vE3);
    if (iters > 1) LOADP(1, aO0, aO1, aO2, aO3, vO0, vO1, vO2, vO3);

    int p = 0;
    for (; p + 2 < iters; p += 2) {
        BODYP(p, aE0, aE1, aE2, aE3, vE0, vE1, vE2, vE3);
        LOADP(p + 2, aE0, aE1, aE2, aE3, vE0, vE1, vE2, vE3);
        BODYP(p + 1, aO0, aO1, aO2, aO3, vO0, vO1, vO2, vO3);
        if (p + 3 < iters) LOADP(p + 3, aO0, aO1, aO2, aO3, vO0, vO1, vO2, vO3);
    }
    BODYP(p, aE0, aE1, aE2, aE3, vE0, vE1, vE2, vE3);
    if (p + 1 < iters) BODYP(p + 1, aO0, aO1, aO2, aO3, vO0, vO1, vO2, vO3);

#undef LOADP
#undef BODYP

    // fold 16 slots: m = mbase + 64*bp + 16*t + 4*lq + j, t = s>>2, j = s&3
    double fb = best[0];
    int    fm = mbase + (bp[0] << 6) + (lq << 2);
#pragma unroll
    for (int s = 1; s < 16; ++s) {
        int ms = mbase + (bp[s] << 6) + ((s >> 2) << 4) + (lq << 2) + (s & 3);
        if (best[s] < fb || (best[s] == fb && ms < fm)) { fb = best[s]; fm = ms; }
    }

    // merge the 4 k-groups holding the same n (lanes l, l^16, l^32, l^48)
#pragma unroll
    for (int off = 16; off <= 32; off <<= 1) {
        double ob = __shfl_xor(fb, off, 64);
        int    om = __shfl_xor(fm, off, 64);
        if (ob < fb || (ob == fb && om < fm)) { fb = ob; fm = om; }
    }
    if (lq == 0) {
        size_t o = ((size_t)(b * nchunk + chunk)) * NPTS + n0 + ncol;
        pscore[o] = fb;
        pidx[o]   = fm;
    }
}

// Merge chunks (ascending, lexicographic) + partial loss.
__global__ void k_mergeloss(const double* __restrict__ pscore,
                            const int* __restrict__ pidx,
                            const float* __restrict__ expd,
                            double* __restrict__ lpart, int nchunk) {
    int gid = blockIdx.x * 256 + threadIdx.x;    // 63*256 = 16128 >= 16000
    double sum = 0.0;
    if (gid < TOTN) {
        int b  = gid / NPTS;
        int nn = gid % NPTS;
        size_t o = ((size_t)(b * nchunk)) * NPTS + nn;
        double b0 = pscore[o];
        int    i0 = pidx[o];
        for (int c = 1; c < nchunk; ++c) {
            double bpv = pscore[o + (size_t)c * NPTS];
            int    ip  = pidx[o + (size_t)c * NPTS];
            if (bpv < b0 || (bpv == b0 && ip < i0)) { b0 = bpv; i0 = ip; }
        }
        double fd = (double)(i0 / 400);
        double fh = (double)((i0 / 20) % 20);
        double fw = (double)(i0 % 20);
        const float* e = expd + (size_t)gid * 3;
        sum = fabs((double)e[0] - fd) + fabs((double)e[1] - fh) + fabs((double)e[2] - fw);
    }
    __shared__ double red[256];
    red[threadIdx.x] = sum;
    __syncthreads();
    for (int s = 128; s > 0; s >>= 1) {
        if (threadIdx.x < s) red[threadIdx.x] += red[threadIdx.x + s];
        __syncthreads();
    }
    if (threadIdx.x == 0) lpart[blockIdx.x] = red[0];
}

__global__ void k_final(const double* __restrict__ lpart, float* __restrict__ out) {
    int lane = threadIdx.x;                      // 64
    double v = (lane < 63) ? lpart[lane] : 0.0;
#pragma unroll
    for (int off = 32; off > 0; off >>= 1) v += __shfl_down(v, off);
    if (lane == 0) out[0] = (float)(v / 48000.0);
}

extern "C" void kernel_launch(void* const* d_in, const int* in_sizes, int n_in,
                              void* d_out, int out_size, void* d_ws, size_t ws_size,
                              hipStream_t stream) {
    const float* src  = (const float*)d_in[0];
    const float* tgt  = (const float*)d_in[1];
    const float* expd = (const float*)d_in[2];

    // nchunk=25 (grid 6250 blocks, 5 bodies of 64 m) needs ~9.03 MB scratch;
    // fall back to nchunk=5 (1250 blocks, 25 bodies).
    int nchunk = 25, mchunk = 320;
    {
        size_t need = 4224000ull + (size_t)BDIM * 25 * NPTS * 12 + 512;
        if (ws_size < need) { nchunk = 5; mchunk = 1600; }
    }

    char* ws = (char*)d_ws;
    double* sfeat2 = (double*)(ws);
    double* tfeat  = (double*)(ws + 2048000);
    double* t2     = (double*)(ws + 4096000);
    double* pscore = (double*)(ws + 4224000);
    size_t  psz    = (size_t)BDIM * nchunk * NPTS * 8;
    int*    pidx   = (int*)(ws + 4224000 + psz);
    size_t  isz    = (size_t)BDIM * nchunk * NPTS * 4;
    double* lpart  = (double*)(ws + 4224000 + psz + isz);

    k_resize   <<<2000, 256, 0, stream>>>(src, tgt, sfeat2, tfeat);
    k_t2       <<<63, 256, 0, stream>>>(tfeat, t2);
    k_argmin   <<<dim3(125, nchunk, BDIM), 256, 0, stream>>>(sfeat2, tfeat, t2,
                                                             pscore, pidx, mchunk, nchunk);
    k_mergeloss<<<63, 256, 0, stream>>>(pscore, pidx, expd, lpart, nchunk);
    k_final    <<<1, 64, 0, stream>>>(lpart, (float*)d_out);
}

// Round 12
// 214.783 us; speedup vs baseline: 1.3217x; 1.3217x over previous
//
#include <hip/hip_runtime.h>
#include <stdint.h>
#include <math.h>

#define BDIM   2
#define CDIM   16
#define INS    64
#define OUTS   20
#define NPTS   8000          // 20^3
#define TOTN   (BDIM*NPTS)   // 16000

using f64x4 = __attribute__((ext_vector_type(4))) double;

#define MFMA64(a, b, c) __builtin_amdgcn_mfma_f64_16x16x4f64((a), (b), (c), 0, 0, 0)

// ---------------- ws layout (bytes, all 8B-aligned) ----------------
// sfeat(-2x): 0        +2,048,000   (B,N,C) f64, pre-scaled by -2
// tfeat     : 2048000  +2,048,000   (B,N,C) f64
// t2        : 4096000  +128,000     (B,N)   f64
// pscore    : 4224000  +B*nchunk*N*8
// pidx      : ...      +B*nchunk*N*4
// lpart     : ...      +504
// ~9.03 MB at nchunk=25 (proven to fit in round 11)

// Trilinear resize 64^3 -> 20^3 matching jax.image.resize(method='trilinear',
// antialias=True). All math in f64. Source features stored pre-scaled by -2
// (exact: power of two) so the MFMA computes t2 - 2*s.t directly.
__global__ void k_resize(const float* __restrict__ src, const float* __restrict__ tgt,
                         double* __restrict__ sfeat2, double* __restrict__ tfeat) {
    __shared__ double wts[OUTS][8];
    __shared__ int    st[OUTS];
    __shared__ int    cnt[OUTS];
    int tid = threadIdx.x;
    if (tid < OUTS) {
        double sample = (tid + 0.5) * 3.2 - 0.5;
        int lo = (int)ceil(sample - 3.2);
        int hi = (int)floor(sample + 3.2);
        if (lo < 0) lo = 0;
        if (hi > INS - 1) hi = INS - 1;
        int c = hi - lo + 1;           // <= 7
        double w[8];
        double sum = 0.0;
        for (int k = 0; k < 8; ++k) {
            double ww = 0.0;
            if (k < c) {
                double x = fabs(sample - (double)(lo + k)) * (1.0 / 3.2);
                ww = (x < 1.0) ? (1.0 - x) : 0.0;
            }
            w[k] = ww; sum += ww;
        }
        for (int k = 0; k < 8; ++k) wts[tid][k] = w[k] / sum;
        st[tid] = lo; cnt[tid] = c;
    }
    __syncthreads();

    int gid = blockIdx.x * blockDim.x + tid;     // [sel][b][c][od][oh][ow], 512000 total
    int ow = gid % OUTS; int r = gid / OUTS;
    int oh = r % OUTS;  r /= OUTS;
    int od = r % OUTS;  r /= OUTS;
    int c  = r % CDIM;  r /= CDIM;
    int b  = r % BDIM;  r /= BDIM;
    int sel = r;                                  // 0=src, 1=tgt

    const float* in   = sel ? tgt : src;
    double*      outf = sel ? tfeat : sfeat2;

    const float* base = in + (((size_t)(b * CDIM + c)) << 18);   // * 64*64*64
    int sd = st[od], sh = st[oh], sw = st[ow];
    int cd = cnt[od], ch = cnt[oh], cw = cnt[ow];
    double wwv[8];
    for (int k = 0; k < 8; ++k) wwv[k] = wts[ow][k];

    double acc = 0.0;
    for (int id = 0; id < cd; ++id) {
        double wd = wts[od][id];
        const float* pd = base + ((size_t)(sd + id) << 12);
        for (int ih = 0; ih < ch; ++ih) {
            double wdh = wd * wts[oh][ih];
            const float* row = pd + ((sh + ih) << 6) + sw;
            for (int iw = 0; iw < cw; ++iw)
                acc = fma(wdh * wwv[iw], (double)row[iw], acc);
        }
    }
    if (sel == 0) acc = -2.0 * acc;               // exact scale
    int n = (od * OUTS + oh) * OUTS + ow;
    outf[((size_t)(b * NPTS + n)) * CDIM + c] = acc;
}

__global__ void k_t2(const double* __restrict__ tfeat, double* __restrict__ t2) {
    int i = blockIdx.x * blockDim.x + threadIdx.x;
    if (i >= TOTN) return;
    const double* p = tfeat + (size_t)i * CDIM;
    double a = 0, b = 0, c = 0, d = 0;
#pragma unroll
    for (int k = 0; k < 4; ++k) {
        a = fma(p[4*k+0], p[4*k+0], a);
        b = fma(p[4*k+1], p[4*k+1], b);
        c = fma(p[4*k+2], p[4*k+2], c);
        d = fma(p[4*k+3], p[4*k+3], d);
    }
    t2[i] = (a + b) + (c + d);
}

// f64-MFMA argmin, round-12: dual n-set per wave.
//  - Each wave owns TWO 16-n strips (n0, n0+64). Per body (32 m), the SAME
//    2 A-tiles + t2 seeds feed 4 MFMA chains (16 MFMAs ~ 1024 cy issue) —
//    2x round-10 compute per buffer register. Buffers stay at round-10 size
//    (the 4-chain-by-m variant of round 11 spilled: WRITE_SIZE 11 MB).
//  - best-state compressed: per (set, tile) = (score, bodyIdx, jIdx), with
//    a per-body j-fold (j ascending = m ascending -> exact earliest-m ties).
//  - calibrated fragment layout + pi-permuted A rows (static D-slot -> m map).
__global__ __launch_bounds__(256, 2) void k_argmin(const double* __restrict__ sfeat2,
                                                   const double* __restrict__ tfeat,
                                                   const double* __restrict__ t2,
                                                   double* __restrict__ pscore,
                                                   int* __restrict__ pidx,
                                                   int mchunk, int nchunk) {
    int b     = blockIdx.z;
    int chunk = blockIdx.y;
    int lane  = threadIdx.x & 63;
    int wp    = threadIdx.x >> 6;                // 0..3
    int nbase = blockIdx.x << 7;                 // 128 n per block
    int n0    = nbase + (wp << 4);               // set-0 strip
    int n1    = n0 + 64;                         // set-1 strip (may pad at tail)
    int lr    = lane & 15;                       // fragment feed index
    int lq    = lane >> 4;                       // k-group 0..3

    // ---- layout calibration + pi table ----
    f64x4 z = {0.0, 0.0, 0.0, 0.0};
    f64x4 calA = MFMA64((double)lr, 0.25, z);
    f64x4 calB = MFMA64(0.25, (double)lr, z);
    int ncol = (int)(calB[0] + 0.5);

    __shared__ int ptab[16];
#pragma unroll
    for (int j = 0; j < 4; ++j) {
        int r = (int)(calA[j] + 0.5);            // hardware feed-row of slot j
        ptab[r] = (lq << 2) + j;                 // pi: feed-row -> desired m-offset
    }
    __syncthreads();
    int prow = ptab[lr];                         // A-row permutation for this lane

    // B fragments for both n-sets (k = 4*lq + kb, contiguous 32B per lane)
    int nn0 = n0 + lr; if (nn0 > NPTS - 1) nn0 = NPTS - 1;
    int nn1 = n1 + lr; if (nn1 > NPTS - 1) nn1 = NPTS - 1;
    const double* sb0 = sfeat2 + ((size_t)(b * NPTS + nn0)) * CDIM + (lq << 2);
    const double* sb1 = sfeat2 + ((size_t)(b * NPTS + nn1)) * CDIM + (lq << 2);
    double b00 = sb0[0], b01 = sb0[1], b02 = sb0[2], b03 = sb0[3];
    double b10 = sb1[0], b11 = sb1[1], b12 = sb1[2], b13 = sb1[3];

    const double* tb  = tfeat + (size_t)b * NPTS * CDIM;
    const double* t2b = t2 + (size_t)b * NPTS;

    int mbase = chunk * mchunk;
    int iters = mchunk >> 5;                     // bodies of 32 m (2 tiles)

    const double* tA = tb + ((size_t)(mbase + prow)) * CDIM + (lq << 2);
    const double* tV = t2b + mbase + (lq << 2);

    // per (set, tile) best state
    double bs00 = 1e300, bs01 = 1e300, bs10 = 1e300, bs11 = 1e300;
    int    ip00 = 0, ip01 = 0, ip10 = 0, ip11 = 0;   // body index
    int    ij00 = 0, ij01 = 0, ij10 = 0, ij11 = 0;   // j index

    f64x4 aE0, aE1, vE0, vE1, aO0, aO1, vO0, vO1;

#define LOADP(P, A0, A1, V0, V1)                                   \
    {  const double* pa_ = tA + (size_t)((P) << 5) * CDIM;         \
       A0 = *(const f64x4*)(pa_);                                  \
       A1 = *(const f64x4*)(pa_ + (CDIM << 4));                    \
       const double* pv_ = tV + ((P) << 5);                        \
       V0 = *(const f64x4*)(pv_);                                  \
       V1 = *(const f64x4*)(pv_ + 16); }

#define FOLD(AC, BS, IP, IJ, P)                                    \
    {  double jb_ = AC[0]; int jj_ = 0;                            \
       if (AC[1] < jb_) { jb_ = AC[1]; jj_ = 1; }                  \
       if (AC[2] < jb_) { jb_ = AC[2]; jj_ = 2; }                  \
       if (AC[3] < jb_) { jb_ = AC[3]; jj_ = 3; }                  \
       if (jb_ < BS) { BS = jb_; IP = (P); IJ = jj_; } }

#define BODYP(P, A0, A1, V0, V1)                                   \
    {  f64x4 a00 = V0, a01 = V1, a10 = V0, a11 = V1;               \
       a00 = MFMA64(A0[0], b00, a00);                              \
       a10 = MFMA64(A0[0], b10, a10);                              \
       a01 = MFMA64(A1[0], b00, a01);                              \
       a11 = MFMA64(A1[0], b10, a11);                              \
       a00 = MFMA64(A0[1], b01, a00);                              \
       a10 = MFMA64(A0[1], b11, a10);                              \
       a01 = MFMA64(A1[1], b01, a01);                              \
       a11 = MFMA64(A1[1], b11, a11);                              \
       a00 = MFMA64(A0[2], b02, a00);                              \
       a10 = MFMA64(A0[2], b12, a10);                              \
       a01 = MFMA64(A1[2], b02, a01);                              \
       a11 = MFMA64(A1[2], b12, a11);                              \
       a00 = MFMA64(A0[3], b03, a00);                              \
       a10 = MFMA64(A0[3], b13, a10);                              \
       a01 = MFMA64(A1[3], b03, a01);                              \
       a11 = MFMA64(A1[3], b13, a11);                              \
       FOLD(a00, bs00, ip00, ij00, P)                              \
       FOLD(a01, bs01, ip01, ij01, P)                              \
       FOLD(a10, bs10, ip10, ij10, P)                              \
       FOLD(a11, bs11, ip11, ij11, P) }

    LOADP(0, aE0, aE1, vE0, vE1);
    if (iters > 1) LOADP(1, aO0, aO1, vO0, vO1);

    int p = 0;
    for (; p + 2 < iters; p += 2) {
        BODYP(p, aE0, aE1, vE0, vE1);
        LOADP(p + 2, aE0, aE1, vE0, vE1);
        BODYP(p + 1, aO0, aO1, vO0, vO1);
        if (p + 3 < iters) LOADP(p + 3, aO0, aO1, vO0, vO1);
    }
    BODYP(p, aE0, aE1, vE0, vE1);
    if (p + 1 < iters) BODYP(p + 1, aO0, aO1, vO0, vO1);

#undef LOADP
#undef FOLD
#undef BODYP

    // reconstruct m and fold tiles per set (lexicographic)
    int m00 = mbase + (ip00 << 5) + (lq << 2) + ij00;
    int m01 = mbase + (ip01 << 5) + 16 + (lq << 2) + ij01;
    int m10 = mbase + (ip10 << 5) + (lq << 2) + ij10;
    int m11 = mbase + (ip11 << 5) + 16 + (lq << 2) + ij11;

    double fb0 = bs00; int fm0 = m00;
    if (bs01 < fb0 || (bs01 == fb0 && m01 < fm0)) { fb0 = bs01; fm0 = m01; }
    double fb1 = bs10; int fm1 = m10;
    if (bs11 < fb1 || (bs11 == fb1 && m11 < fm1)) { fb1 = bs11; fm1 = m11; }

    // merge the 4 k-groups holding the same n (lanes l, l^16, l^32, l^48)
#pragma unroll
    for (int off = 16; off <= 32; off <<= 1) {
        double ob = __shfl_xor(fb0, off, 64);
        int    om = __shfl_xor(fm0, off, 64);
        if (ob < fb0 || (ob == fb0 && om < fm0)) { fb0 = ob; fm0 = om; }
        double ob1 = __shfl_xor(fb1, off, 64);
        int    om1 = __shfl_xor(fm1, off, 64);
        if (ob1 < fb1 || (ob1 == fb1 && om1 < fm1)) { fb1 = ob1; fm1 = om1; }
    }
    if (lq == 0) {
        size_t base = ((size_t)(b * nchunk + chunk)) * NPTS;
        int ns0 = n0 + ncol;                     // always < NPTS
        pscore[base + ns0] = fb0;
        pidx[base + ns0]   = fm0;
        int ns1 = n1 + ncol;
        if (ns1 < NPTS) {
            pscore[base + ns1] = fb1;
            pidx[base + ns1]   = fm1;
        }
    }
}

// Merge chunks (ascending, lexicographic) + partial loss.
__global__ void k_mergeloss(const double* __restrict__ pscore,
                            const int* __restrict__ pidx,
                            const float* __restrict__ expd,
                            double* __restrict__ lpart, int nchunk) {
    int gid = blockIdx.x * 256 + threadIdx.x;    // 63*256 = 16128 >= 16000
    double sum = 0.0;
    if (gid < TOTN) {
        int b  = gid / NPTS;
        int nn = gid % NPTS;
        size_t o = ((size_t)(b * nchunk)) * NPTS + nn;
        double b0 = pscore[o];
        int    i0 = pidx[o];
        for (int c = 1; c < nchunk; ++c) {
            double bpv = pscore[o + (size_t)c * NPTS];
            int    ip  = pidx[o + (size_t)c * NPTS];
            if (bpv < b0 || (bpv == b0 && ip < i0)) { b0 = bpv; i0 = ip; }
        }
        double fd = (double)(i0 / 400);
        double fh = (double)((i0 / 20) % 20);
        double fw = (double)(i0 % 20);
        const float* e = expd + (size_t)gid * 3;
        sum = fabs((double)e[0] - fd) + fabs((double)e[1] - fh) + fabs((double)e[2] - fw);
    }
    __shared__ double red[256];
    red[threadIdx.x] = sum;
    __syncthreads();
    for (int s = 128; s > 0; s >>= 1) {
        if (threadIdx.x < s) red[threadIdx.x] += red[threadIdx.x + s];
        __syncthreads();
    }
    if (threadIdx.x == 0) lpart[blockIdx.x] = red[0];
}

__global__ void k_final(const double* __restrict__ lpart, float* __restrict__ out) {
    int lane = threadIdx.x;                      // 64
    double v = (lane < 63) ? lpart[lane] : 0.0;
#pragma unroll
    for (int off = 32; off > 0; off >>= 1) v += __shfl_down(v, off);
    if (lane == 0) out[0] = (float)(v / 48000.0);
}

extern "C" void kernel_launch(void* const* d_in, const int* in_sizes, int n_in,
                              void* d_out, int out_size, void* d_ws, size_t ws_size,
                              hipStream_t stream) {
    const float* src  = (const float*)d_in[0];
    const float* tgt  = (const float*)d_in[1];
    const float* expd = (const float*)d_in[2];

    // nchunk=25 (10 bodies of 32 m) needs ~9.03 MB scratch (proven);
    // fall back to nchunk=5 (50 bodies).
    int nchunk = 25, mchunk = 320;
    {
        size_t need = 4224000ull + (size_t)BDIM * 25 * NPTS * 12 + 512;
        if (ws_size < need) { nchunk = 5; mchunk = 1600; }
    }

    char* ws = (char*)d_ws;
    double* sfeat2 = (double*)(ws);
    double* tfeat  = (double*)(ws + 2048000);
    double* t2     = (double*)(ws + 4096000);
    double* pscore = (double*)(ws + 4224000);
    size_t  psz    = (size_t)BDIM * nchunk * NPTS * 8;
    int*    pidx   = (int*)(ws + 4224000 + psz);
    size_t  isz    = (size_t)BDIM * nchunk * NPTS * 4;
    double* lpart  = (double*)(ws + 4224000 + psz + isz);

    k_resize   <<<2000, 256, 0, stream>>>(src, tgt, sfeat2, tfeat);
    k_t2       <<<63, 256, 0, stream>>>(tfeat, t2);
    k_argmin   <<<dim3(63, nchunk, BDIM), 256, 0, stream>>>(sfeat2, tfeat, t2,
                                                            pscore, pidx, mchunk, nchunk);
    k_mergeloss<<<63, 256, 0, stream>>>(pscore, pidx, expd, lpart, nchunk);
    k_final    <<<1, 64, 0, stream>>>(lpart, (float*)d_out);
}

// Round 13
// 142.660 us; speedup vs baseline: 1.9899x; 1.5056x over previous
//
#include <hip/hip_runtime.h>
#include <stdint.h>
#include <math.h>

#define BDIM   2
#define CDIM   16
#define INS    64
#define OUTS   20
#define NPTS   8000          // 20^3
#define TOTN   (BDIM*NPTS)   // 16000

using f64x4 = __attribute__((ext_vector_type(4))) double;

#define MFMA64(a, b, c) __builtin_amdgcn_mfma_f64_16x16x4f64((a), (b), (c), 0, 0, 0)

// ---------------- ws layout (bytes, all 8B-aligned) ----------------
// sfeat(-2x): 0        +2,048,000   (B,N,C) f64, pre-scaled by -2
// tfeat     : 2048000  +2,048,000   (B,N,C) f64
// t2        : 4096000  +128,000     (B,N)   f64
// pscore    : 4224000  +B*nchunk*N*8
// pidx      : ...      +B*nchunk*N*4
// lpart     : ...      +504
// ~9.03 MB at nchunk=25 (proven to fit)

// Separable trilinear resize 64^3 -> 20^3 matching jax.image.resize
// (method='trilinear', antialias=True): triangle kernel scaled by 3.2,
// valid-tap renormalization — identical per-dim weight tables as the
// verified gather version; separable application (d, then h, then w) in
// f64 differs only at ~1e-16 relative (argmin-safe; round-2 analysis).
// One block per (sel, b, c, od). d-stage register-accumulated with
// coalesced loads; h/w stages through LDS.
__global__ __launch_bounds__(256) void k_resize(const float* __restrict__ src,
                                                const float* __restrict__ tgt,
                                                double* __restrict__ sfeat2,
                                                double* __restrict__ tfeat) {
    __shared__ double wts[OUTS][8];
    __shared__ int    st[OUTS];
    __shared__ int    cnt[OUTS];
    __shared__ double plane[INS * INS];          // 32 KB
    __shared__ double hplane[OUTS * INS];        // 10 KB

    int tid = threadIdx.x;
    if (tid < OUTS) {
        double sample = (tid + 0.5) * 3.2 - 0.5;
        int lo = (int)ceil(sample - 3.2);
        int hi = (int)floor(sample + 3.2);
        if (lo < 0) lo = 0;
        if (hi > INS - 1) hi = INS - 1;
        int c = hi - lo + 1;           // <= 7
        double w[8];
        double sum = 0.0;
        for (int k = 0; k < 8; ++k) {
            double ww = 0.0;
            if (k < c) {
                double x = fabs(sample - (double)(lo + k)) * (1.0 / 3.2);
                ww = (x < 1.0) ? (1.0 - x) : 0.0;
            }
            w[k] = ww; sum += ww;
        }
        for (int k = 0; k < 8; ++k) wts[tid][k] = w[k] / sum;
        st[tid] = lo; cnt[tid] = c;
    }
    __syncthreads();

    int od  = blockIdx.x;                        // 0..19
    int c   = blockIdx.y;                        // 0..15
    int sb  = blockIdx.z;                        // 0..3
    int sel = sb >> 1;
    int b   = sb & 1;

    const float* in = (sel ? tgt : src) + (((size_t)(b * CDIM + c)) << 18);

    // ---- d-stage: plane[h][w] = sum_d wd * in[d][h][w], registers ----
    int sd = st[od], cd = cnt[od];
    double acc[16];
#pragma unroll
    for (int i = 0; i < 16; ++i) acc[i] = 0.0;
    for (int t = 0; t < cd; ++t) {
        double wd = wts[od][t];
        const float* p = in + (((size_t)(sd + t)) << 12) + tid;
#pragma unroll
        for (int i = 0; i < 16; ++i)
            acc[i] = fma(wd, (double)p[i << 8], acc[i]);
    }
#pragma unroll
    for (int i = 0; i < 16; ++i) plane[tid + (i << 8)] = acc[i];
    __syncthreads();

    // ---- h-stage: hplane[oh][w] = sum_h wh * plane[h][w] ----
    for (int e = tid; e < OUTS * INS; e += 256) {
        int oh = e >> 6, w = e & 63;
        int sh = st[oh], ch = cnt[oh];
        double a = 0.0;
        for (int t = 0; t < ch; ++t)
            a = fma(wts[oh][t], plane[((sh + t) << 6) + w], a);
        hplane[e] = a;
    }
    __syncthreads();

    // ---- w-stage: out[oh][ow] = sum_w ww * hplane[oh][w] ----
    double* outf = sel ? tfeat : sfeat2;
    for (int e = tid; e < OUTS * OUTS; e += 256) {
        int oh = e / OUTS, ow = e - oh * OUTS;
        int sw = st[ow], cw = cnt[ow];
        const double* hp = &hplane[(oh << 6) + sw];
        double a = 0.0;
        for (int t = 0; t < cw; ++t)
            a = fma(wts[ow][t], hp[t], a);
        if (sel == 0) a = -2.0 * a;              // exact scale
        int n = (od * OUTS + oh) * OUTS + ow;
        outf[((size_t)(b * NPTS + n)) * CDIM + c] = a;
    }
}

__global__ void k_t2(const double* __restrict__ tfeat, double* __restrict__ t2) {
    int i = blockIdx.x * blockDim.x + threadIdx.x;
    if (i >= TOTN) return;
    const double* p = tfeat + (size_t)i * CDIM;
    double a = 0, b = 0, c = 0, d = 0;
#pragma unroll
    for (int k = 0; k < 4; ++k) {
        a = fma(p[4*k+0], p[4*k+0], a);
        b = fma(p[4*k+1], p[4*k+1], b);
        c = fma(p[4*k+2], p[4*k+2], c);
        d = fma(p[4*k+3], p[4*k+3], d);
    }
    t2[i] = (a + b) + (c + d);
}

// f64-MFMA argmin (round-12 structure, unchanged — dual n-set per wave).
__global__ __launch_bounds__(256, 2) void k_argmin(const double* __restrict__ sfeat2,
                                                   const double* __restrict__ tfeat,
                                                   const double* __restrict__ t2,
                                                   double* __restrict__ pscore,
                                                   int* __restrict__ pidx,
                                                   int mchunk, int nchunk) {
    int b     = blockIdx.z;
    int chunk = blockIdx.y;
    int lane  = threadIdx.x & 63;
    int wp    = threadIdx.x >> 6;                // 0..3
    int nbase = blockIdx.x << 7;                 // 128 n per block
    int n0    = nbase + (wp << 4);               // set-0 strip
    int n1    = n0 + 64;                         // set-1 strip (may pad at tail)
    int lr    = lane & 15;                       // fragment feed index
    int lq    = lane >> 4;                       // k-group 0..3

    // ---- layout calibration + pi table ----
    f64x4 z = {0.0, 0.0, 0.0, 0.0};
    f64x4 calA = MFMA64((double)lr, 0.25, z);
    f64x4 calB = MFMA64(0.25, (double)lr, z);
    int ncol = (int)(calB[0] + 0.5);

    __shared__ int ptab[16];
#pragma unroll
    for (int j = 0; j < 4; ++j) {
        int r = (int)(calA[j] + 0.5);            // hardware feed-row of slot j
        ptab[r] = (lq << 2) + j;                 // pi: feed-row -> desired m-offset
    }
    __syncthreads();
    int prow = ptab[lr];                         // A-row permutation for this lane

    // B fragments for both n-sets (k = 4*lq + kb, contiguous 32B per lane)
    int nn0 = n0 + lr; if (nn0 > NPTS - 1) nn0 = NPTS - 1;
    int nn1 = n1 + lr; if (nn1 > NPTS - 1) nn1 = NPTS - 1;
    const double* sb0 = sfeat2 + ((size_t)(b * NPTS + nn0)) * CDIM + (lq << 2);
    const double* sb1 = sfeat2 + ((size_t)(b * NPTS + nn1)) * CDIM + (lq << 2);
    double b00 = sb0[0], b01 = sb0[1], b02 = sb0[2], b03 = sb0[3];
    double b10 = sb1[0], b11 = sb1[1], b12 = sb1[2], b13 = sb1[3];

    const double* tb  = tfeat + (size_t)b * NPTS * CDIM;
    const double* t2b = t2 + (size_t)b * NPTS;

    int mbase = chunk * mchunk;
    int iters = mchunk >> 5;                     // bodies of 32 m (2 tiles)

    const double* tA = tb + ((size_t)(mbase + prow)) * CDIM + (lq << 2);
    const double* tV = t2b + mbase + (lq << 2);

    // per (set, tile) best state
    double bs00 = 1e300, bs01 = 1e300, bs10 = 1e300, bs11 = 1e300;
    int    ip00 = 0, ip01 = 0, ip10 = 0, ip11 = 0;   // body index
    int    ij00 = 0, ij01 = 0, ij10 = 0, ij11 = 0;   // j index

    f64x4 aE0, aE1, vE0, vE1, aO0, aO1, vO0, vO1;

#define LOADP(P, A0, A1, V0, V1)                                   \
    {  const double* pa_ = tA + (size_t)((P) << 5) * CDIM;         \
       A0 = *(const f64x4*)(pa_);                                  \
       A1 = *(const f64x4*)(pa_ + (CDIM << 4));                    \
       const double* pv_ = tV + ((P) << 5);                        \
       V0 = *(const f64x4*)(pv_);                                  \
       V1 = *(const f64x4*)(pv_ + 16); }

#define FOLD(AC, BS, IP, IJ, P)                                    \
    {  double jb_ = AC[0]; int jj_ = 0;                            \
       if (AC[1] < jb_) { jb_ = AC[1]; jj_ = 1; }                  \
       if (AC[2] < jb_) { jb_ = AC[2]; jj_ = 2; }                  \
       if (AC[3] < jb_) { jb_ = AC[3]; jj_ = 3; }                  \
       if (jb_ < BS) { BS = jb_; IP = (P); IJ = jj_; } }

#define BODYP(P, A0, A1, V0, V1)                                   \
    {  f64x4 a00 = V0, a01 = V1, a10 = V0, a11 = V1;               \
       a00 = MFMA64(A0[0], b00, a00);                              \
       a10 = MFMA64(A0[0], b10, a10);                              \
       a01 = MFMA64(A1[0], b00, a01);                              \
       a11 = MFMA64(A1[0], b10, a11);                              \
       a00 = MFMA64(A0[1], b01, a00);                              \
       a10 = MFMA64(A0[1], b11, a10);                              \
       a01 = MFMA64(A1[1], b01, a01);                              \
       a11 = MFMA64(A1[1], b11, a11);                              \
       a00 = MFMA64(A0[2], b02, a00);                              \
       a10 = MFMA64(A0[2], b12, a10);                              \
       a01 = MFMA64(A1[2], b02, a01);                              \
       a11 = MFMA64(A1[2], b12, a11);                              \
       a00 = MFMA64(A0[3], b03, a00);                              \
       a10 = MFMA64(A0[3], b13, a10);                              \
       a01 = MFMA64(A1[3], b03, a01);                              \
       a11 = MFMA64(A1[3], b13, a11);                              \
       FOLD(a00, bs00, ip00, ij00, P)                              \
       FOLD(a01, bs01, ip01, ij01, P)                              \
       FOLD(a10, bs10, ip10, ij10, P)                              \
       FOLD(a11, bs11, ip11, ij11, P) }

    LOADP(0, aE0, aE1, vE0, vE1);
    if (iters > 1) LOADP(1, aO0, aO1, vO0, vO1);

    int p = 0;
    for (; p + 2 < iters; p += 2) {
        BODYP(p, aE0, aE1, vE0, vE1);
        LOADP(p + 2, aE0, aE1, vE0, vE1);
        BODYP(p + 1, aO0, aO1, vO0, vO1);
        if (p + 3 < iters) LOADP(p + 3, aO0, aO1, vO0, vO1);
    }
    BODYP(p, aE0, aE1, vE0, vE1);
    if (p + 1 < iters) BODYP(p + 1, aO0, aO1, vO0, vO1);

#undef LOADP
#undef FOLD
#undef BODYP

    // reconstruct m and fold tiles per set (lexicographic)
    int m00 = mbase + (ip00 << 5) + (lq << 2) + ij00;
    int m01 = mbase + (ip01 << 5) + 16 + (lq << 2) + ij01;
    int m10 = mbase + (ip10 << 5) + (lq << 2) + ij10;
    int m11 = mbase + (ip11 << 5) + 16 + (lq << 2) + ij11;

    double fb0 = bs00; int fm0 = m00;
    if (bs01 < fb0 || (bs01 == fb0 && m01 < fm0)) { fb0 = bs01; fm0 = m01; }
    double fb1 = bs10; int fm1 = m10;
    if (bs11 < fb1 || (bs11 == fb1 && m11 < fm1)) { fb1 = bs11; fm1 = m11; }

    // merge the 4 k-groups holding the same n (lanes l, l^16, l^32, l^48)
#pragma unroll
    for (int off = 16; off <= 32; off <<= 1) {
        double ob = __shfl_xor(fb0, off, 64);
        int    om = __shfl_xor(fm0, off, 64);
        if (ob < fb0 || (ob == fb0 && om < fm0)) { fb0 = ob; fm0 = om; }
        double ob1 = __shfl_xor(fb1, off, 64);
        int    om1 = __shfl_xor(fm1, off, 64);
        if (ob1 < fb1 || (ob1 == fb1 && om1 < fm1)) { fb1 = ob1; fm1 = om1; }
    }
    if (lq == 0) {
        size_t base = ((size_t)(b * nchunk + chunk)) * NPTS;
        int ns0 = n0 + ncol;                     // always < NPTS
        pscore[base + ns0] = fb0;
        pidx[base + ns0]   = fm0;
        int ns1 = n1 + ncol;
        if (ns1 < NPTS) {
            pscore[base + ns1] = fb1;
            pidx[base + ns1]   = fm1;
        }
    }
}

// Merge chunks (ascending, lexicographic) + partial loss.
__global__ void k_mergeloss(const double* __restrict__ pscore,
                            const int* __restrict__ pidx,
                            const float* __restrict__ expd,
                            double* __restrict__ lpart, int nchunk) {
    int gid = blockIdx.x * 256 + threadIdx.x;    // 63*256 = 16128 >= 16000
    double sum = 0.0;
    if (gid < TOTN) {
        int b  = gid / NPTS;
        int nn = gid % NPTS;
        size_t o = ((size_t)(b * nchunk)) * NPTS + nn;
        double b0 = pscore[o];
        int    i0 = pidx[o];
        for (int c = 1; c < nchunk; ++c) {
            double bpv = pscore[o + (size_t)c * NPTS];
            int    ip  = pidx[o + (size_t)c * NPTS];
            if (bpv < b0 || (bpv == b0 && ip < i0)) { b0 = bpv; i0 = ip; }
        }
        double fd = (double)(i0 / 400);
        double fh = (double)((i0 / 20) % 20);
        double fw = (double)(i0 % 20);
        const float* e = expd + (size_t)gid * 3;
        sum = fabs((double)e[0] - fd) + fabs((double)e[1] - fh) + fabs((double)e[2] - fw);
    }
    __shared__ double red[256];
    red[threadIdx.x] = sum;
    __syncthreads();
    for (int s = 128; s > 0; s >>= 1) {
        if (threadIdx.x < s) red[threadIdx.x] += red[threadIdx.x + s];
        __syncthreads();
    }
    if (threadIdx.x == 0) lpart[blockIdx.x] = red[0];
}

__global__ void k_final(const double* __restrict__ lpart, float* __restrict__ out) {
    int lane = threadIdx.x;                      // 64
    double v = (lane < 63) ? lpart[lane] : 0.0;
#pragma unroll
    for (int off = 32; off > 0; off >>= 1) v += __shfl_down(v, off);
    if (lane == 0) out[0] = (float)(v / 48000.0);
}

extern "C" void kernel_launch(void* const* d_in, const int* in_sizes, int n_in,
                              void* d_out, int out_size, void* d_ws, size_t ws_size,
                              hipStream_t stream) {
    const float* src  = (const float*)d_in[0];
    const float* tgt  = (const float*)d_in[1];
    const float* expd = (const float*)d_in[2];

    // nchunk=25 (10 bodies of 32 m) needs ~9.03 MB scratch (proven);
    // fall back to nchunk=5 (50 bodies).
    int nchunk = 25, mchunk = 320;
    {
        size_t need = 4224000ull + (size_t)BDIM * 25 * NPTS * 12 + 512;
        if (ws_size < need) { nchunk = 5; mchunk = 1600; }
    }

    char* ws = (char*)d_ws;
    double* sfeat2 = (double*)(ws);
    double* tfeat  = (double*)(ws + 2048000);
    double* t2     = (double*)(ws + 4096000);
    double* pscore = (double*)(ws + 4224000);
    size_t  psz    = (size_t)BDIM * nchunk * NPTS * 8;
    int*    pidx   = (int*)(ws + 4224000 + psz);
    size_t  isz    = (size_t)BDIM * nchunk * NPTS * 4;
    double* lpart  = (double*)(ws + 4224000 + psz + isz);

    k_resize   <<<dim3(OUTS, CDIM, 4), 256, 0, stream>>>(src, tgt, sfeat2, tfeat);
    k_t2       <<<63, 256, 0, stream>>>(tfeat, t2);
    k_argmin   <<<dim3(63, nchunk, BDIM), 256, 0, stream>>>(sfeat2, tfeat, t2,
                                                            pscore, pidx, mchunk, nchunk);
    k_mergeloss<<<63, 256, 0, stream>>>(pscore, pidx, expd, lpart, nchunk);
    k_final    <<<1, 64, 0, stream>>>(lpart, (float*)d_out);
}